// Round 1
// baseline (740.052 us; speedup 1.0000x reference)
//
#include <hip/hip_runtime.h>

#define D_IN  128
#define D_HID 128
#define D_OUT 64

// ---------------------------------------------------------------- degrees
__global__ void k_degree(const int* __restrict__ src, const int* __restrict__ dst,
                         float* __restrict__ cnt_out, float* __restrict__ cnt_in, int E) {
    int i = blockIdx.x * blockDim.x + threadIdx.x;
    int stride = gridDim.x * blockDim.x;
    for (; i < E; i += stride) {
        atomicAdd(&cnt_out[src[i]], 1.0f);
        atomicAdd(&cnt_in[dst[i]], 1.0f);
    }
}

__global__ void k_invsqrt(const float* __restrict__ cnt_out, const float* __restrict__ cnt_in,
                          float* __restrict__ inv_out, float* __restrict__ inv_in, int N) {
    int i = blockIdx.x * blockDim.x + threadIdx.x;
    if (i < N) {
        inv_out[i] = rsqrtf(fmaxf(cnt_out[i], 1.0f));
        inv_in[i]  = rsqrtf(fmaxf(cnt_in[i],  1.0f));
    }
}

// ---------------------------------------------------------------- GEMM
// Y[i][j] = sum_k X[i][k] * scale_i * W[k][j]      (scale optional)
// block = 256 threads, handles ROWS rows of X. W staged in LDS in 2 halves.
template<int DOUT, int ROWS>
__launch_bounds__(256)
__global__ void k_gemm(const float* __restrict__ X, const float* __restrict__ W,
                       const float* __restrict__ scale, float* __restrict__ Y, int N) {
    __shared__ float Wl[64 * DOUT];       // half of W (k = 0..63 or 64..127)
    __shared__ float Xl[ROWS][D_IN];

    const int row0 = blockIdx.x * ROWS;

    // load X rows (scaled) into LDS
    for (int idx = threadIdx.x; idx < ROWS * D_IN; idx += 256) {
        int r = idx >> 7, c = idx & 127;
        int gr = row0 + r;
        float v = 0.0f;
        if (gr < N) {
            v = X[(long long)gr * D_IN + c];
            if (scale) v *= scale[gr];
        }
        Xl[r][c] = v;
    }

    const int j  = threadIdx.x % DOUT;
    const int rg = threadIdx.x / DOUT;        // row group
    constexpr int RG = 256 / DOUT;
    constexpr int M  = ROWS / RG;             // rows per thread

    float acc[M];
#pragma unroll
    for (int m = 0; m < M; ++m) acc[m] = 0.0f;

#pragma unroll
    for (int half = 0; half < 2; ++half) {
        __syncthreads();
        // stage W[half*64 .. half*64+63][0..DOUT) into LDS
        for (int idx = threadIdx.x; idx < 64 * DOUT; idx += 256)
            Wl[idx] = W[half * 64 * DOUT + idx];
        __syncthreads();
#pragma unroll 4
        for (int k = 0; k < 64; ++k) {
            float w = Wl[k * DOUT + j];
#pragma unroll
            for (int m = 0; m < M; ++m)
                acc[m] += Xl[rg * M + m][half * 64 + k] * w;
        }
    }

#pragma unroll
    for (int m = 0; m < M; ++m) {
        int gr = row0 + rg * M + m;
        if (gr < N) Y[(long long)gr * DOUT + j] = acc[m];
    }
}

// ---------------------------------------------------------------- scatter
// agg[dst[e]][j] += Y[src[e]][j]  — D threads per edge, exact grid.
template<int D, int LOG2D>
__launch_bounds__(256)
__global__ void k_scatter(const int* __restrict__ src, const int* __restrict__ dst,
                          const float* __restrict__ Y, float* __restrict__ agg) {
    unsigned int tid = blockIdx.x * 256u + threadIdx.x;
    int e = (int)(tid >> LOG2D);
    int j = (int)(tid & (D - 1));
    int s = src[e], d = dst[e];
    float v = Y[(long long)s * D + j];
    atomicAdd(&agg[(long long)d * D + j], v);
}

// ---------------------------------------------------------------- elementwise
// h = relu(agg*inv_in[i] + b[j]) * inv_out[i]   (in place, prepares layer-2 input)
__global__ void k_relu_scale(float* __restrict__ h, const float* __restrict__ inv_in,
                             const float* __restrict__ inv_out, const float* __restrict__ b,
                             int total) {
    int tid = blockIdx.x * blockDim.x + threadIdx.x;
    if (tid < total) {
        int i = tid >> 7, j = tid & 127;
        float v = h[tid] * inv_in[i] + b[j];
        h[tid] = fmaxf(v, 0.0f) * inv_out[i];
    }
}

__global__ void k_final(const float* __restrict__ agg, const float* __restrict__ inv_in,
                        const float* __restrict__ b, float* __restrict__ out, int total) {
    int tid = blockIdx.x * blockDim.x + threadIdx.x;
    if (tid < total) {
        int i = tid >> 6, j = tid & 63;
        out[tid] = agg[tid] * inv_in[i] + b[j];
    }
}

// ---------------------------------------------------------------- launch
extern "C" void kernel_launch(void* const* d_in, const int* in_sizes, int n_in,
                              void* d_out, int out_size, void* d_ws, size_t ws_size,
                              hipStream_t stream) {
    const int*   src = (const int*)d_in[0];
    const int*   dst = (const int*)d_in[1];
    const float* x   = (const float*)d_in[2];
    const float* W1  = (const float*)d_in[3];
    const float* b1  = (const float*)d_in[4];
    const float* W2  = (const float*)d_in[5];
    const float* b2  = (const float*)d_in[6];
    float* out = (float*)d_out;

    const int E = in_sizes[0];
    const int N = in_sizes[2] / D_IN;

    // workspace layout
    char* ws = (char*)d_ws;
    size_t off = 0;
    auto alloc = [&](size_t bytes) -> void* {
        void* p = ws + off;
        off += (bytes + 255) & ~(size_t)255;
        return p;
    };
    float* cnt_out = (float*)alloc((size_t)N * 4);
    float* cnt_in  = (float*)alloc((size_t)N * 4);
    float* inv_out = (float*)alloc((size_t)N * 4);
    float* inv_in  = (float*)alloc((size_t)N * 4);
    float* Y1      = (float*)alloc((size_t)N * D_HID * 4);
    float* agg1    = (float*)alloc((size_t)N * D_HID * 4);
    float* Y2      = (float*)alloc((size_t)N * D_OUT * 4);
    float* agg2    = (float*)alloc((size_t)N * D_OUT * 4);
    (void)ws_size; (void)n_in; (void)out_size;

    hipMemsetAsync(cnt_out, 0, (size_t)N * 4, stream);
    hipMemsetAsync(cnt_in,  0, (size_t)N * 4, stream);
    hipMemsetAsync(agg1, 0, (size_t)N * D_HID * 4, stream);
    hipMemsetAsync(agg2, 0, (size_t)N * D_OUT * 4, stream);

    k_degree<<<1024, 256, 0, stream>>>(src, dst, cnt_out, cnt_in, E);
    k_invsqrt<<<(N + 255) / 256, 256, 0, stream>>>(cnt_out, cnt_in, inv_out, inv_in, N);

    // layer 1: Y1 = (x * inv_out) @ W1 ; agg1 = scatter ; h1 = relu(agg1*inv_in+b1)*inv_out
    k_gemm<D_HID, 8><<<(N + 7) / 8, 256, 0, stream>>>(x, W1, inv_out, Y1, N);
    k_scatter<D_HID, 7><<<(unsigned)(((long long)E * D_HID) / 256), 256, 0, stream>>>(src, dst, Y1, agg1);
    k_relu_scale<<<(N * D_HID + 255) / 256, 256, 0, stream>>>(agg1, inv_in, inv_out, b1, N * D_HID);

    // layer 2: Y2 = h1s @ W2 ; agg2 = scatter ; out = agg2*inv_in + b2
    k_gemm<D_OUT, 8><<<(N + 7) / 8, 256, 0, stream>>>(agg1, W2, nullptr, Y2, N);
    k_scatter<D_OUT, 6><<<(unsigned)(((long long)E * D_OUT) / 256), 256, 0, stream>>>(src, dst, Y2, agg2);
    k_final<<<(N * D_OUT + 255) / 256, 256, 0, stream>>>(agg2, inv_in, b2, out, N * D_OUT);
}

// Round 2
// 462.471 us; speedup vs baseline: 1.6002x; 1.6002x over previous
//
#include <hip/hip_runtime.h>

#define D_IN  128
#define D_HID 128
#define D_OUT 64
#define SCAN_T 1024

// ---------------------------------------------------------------- histograms (int)
__global__ void k_hist(const int* __restrict__ src, const int* __restrict__ dst,
                       int* __restrict__ hist_out, int* __restrict__ hist_in, int E) {
    int i = blockIdx.x * blockDim.x + threadIdx.x;
    int stride = gridDim.x * blockDim.x;
    for (; i < E; i += stride) {
        atomicAdd(&hist_out[src[i]], 1);
        atomicAdd(&hist_in[dst[i]], 1);
    }
}

__global__ void k_invsqrt(const int* __restrict__ hist_out, const int* __restrict__ hist_in,
                          float* __restrict__ inv_out, float* __restrict__ inv_in, int N) {
    int i = blockIdx.x * blockDim.x + threadIdx.x;
    if (i < N) {
        inv_out[i] = rsqrtf((float)max(hist_out[i], 1));
        inv_in[i]  = rsqrtf((float)max(hist_in[i],  1));
    }
}

// ---------------------------------------------------------------- exclusive scan (1 block)
__launch_bounds__(SCAN_T)
__global__ void k_scan(const int* __restrict__ hist, int* __restrict__ rowptr,
                       int* __restrict__ cursor, int N) {
    __shared__ int part[SCAN_T];
    const int t = threadIdx.x;
    const int C = (N + SCAN_T - 1) / SCAN_T;
    const int lo = t * C;
    const int hi = min(lo + C, N);
    int s = 0;
    for (int i = lo; i < hi; ++i) s += hist[i];
    part[t] = s;
    __syncthreads();
    // Hillis-Steele inclusive scan over partials
    for (int off = 1; off < SCAN_T; off <<= 1) {
        int v = (t >= off) ? part[t - off] : 0;
        __syncthreads();
        part[t] += v;
        __syncthreads();
    }
    int run = (t == 0) ? 0 : part[t - 1];
    for (int i = lo; i < hi; ++i) {
        rowptr[i] = run;
        cursor[i] = run;
        run += hist[i];
    }
    if (t == SCAN_T - 1) rowptr[N] = run;
}

// ---------------------------------------------------------------- CSR fill
__global__ void k_fill(const int* __restrict__ src, const int* __restrict__ dst,
                       int* __restrict__ cursor, int* __restrict__ csr_src, int E) {
    int i = blockIdx.x * blockDim.x + threadIdx.x;
    int stride = gridDim.x * blockDim.x;
    for (; i < E; i += stride) {
        int pos = atomicAdd(&cursor[dst[i]], 1);
        csr_src[pos] = src[i];
    }
}

// ---------------------------------------------------------------- GEMM
// Y[i][j] = sum_k X[i][k] * scale_i * W[k][j]      (scale optional)
template<int DOUT, int ROWS>
__launch_bounds__(256)
__global__ void k_gemm(const float* __restrict__ X, const float* __restrict__ W,
                       const float* __restrict__ scale, float* __restrict__ Y, int N) {
    __shared__ float Wl[64 * DOUT];       // half of W (k = 0..63 or 64..127)
    __shared__ float Xl[ROWS][D_IN];

    const int row0 = blockIdx.x * ROWS;

    for (int idx = threadIdx.x; idx < ROWS * D_IN; idx += 256) {
        int r = idx >> 7, c = idx & 127;
        int gr = row0 + r;
        float v = 0.0f;
        if (gr < N) {
            v = X[(long long)gr * D_IN + c];
            if (scale) v *= scale[gr];
        }
        Xl[r][c] = v;
    }

    const int j  = threadIdx.x % DOUT;
    const int rg = threadIdx.x / DOUT;
    constexpr int RG = 256 / DOUT;
    constexpr int M  = ROWS / RG;

    float acc[M];
#pragma unroll
    for (int m = 0; m < M; ++m) acc[m] = 0.0f;

#pragma unroll
    for (int half = 0; half < 2; ++half) {
        __syncthreads();
        for (int idx = threadIdx.x; idx < 64 * DOUT; idx += 256)
            Wl[idx] = W[half * 64 * DOUT + idx];
        __syncthreads();
#pragma unroll 4
        for (int k = 0; k < 64; ++k) {
            float w = Wl[k * DOUT + j];
#pragma unroll
            for (int m = 0; m < M; ++m)
                acc[m] += Xl[rg * M + m][half * 64 + k] * w;
        }
    }

#pragma unroll
    for (int m = 0; m < M; ++m) {
        int gr = row0 + rg * M + m;
        if (gr < N) Y[(long long)gr * DOUT + j] = acc[m];
    }
}

// ---------------------------------------------------------------- CSR gather
// out[i] = f( sum_{e in CSR(i)} Y[csr_src[e]] )
// One wave (64 lanes) per destination node. D=128: 2 floats/lane; D=64: 1.
template<int D, bool RELU>
__launch_bounds__(256)
__global__ void k_gather(const int* __restrict__ rowptr, const int* __restrict__ csr_src,
                         const float* __restrict__ Y, const float* __restrict__ inv_in,
                         const float* __restrict__ inv_out, const float* __restrict__ b,
                         float* __restrict__ out, int N) {
    const int wid  = (int)((blockIdx.x * 256u + threadIdx.x) >> 6);
    const int lane = threadIdx.x & 63;
    if (wid >= N) return;

    const int start = rowptr[wid];
    const int end   = rowptr[wid + 1];

    float acc0 = 0.0f, acc1 = 0.0f;
    for (int k = start; k < end; k += 64) {
        const int idx = k + lane;
        const int sv  = (idx < end) ? csr_src[idx] : 0;
        const int cnt = min(64, end - k);
        for (int j = 0; j < cnt; ++j) {
            const int s = __shfl(sv, j);
            if (D == 128) {
                float2 v = *(const float2*)(Y + (long long)s * D + 2 * lane);
                acc0 += v.x; acc1 += v.y;
            } else {
                acc0 += Y[(long long)s * D + lane];
            }
        }
    }

    const float ii = inv_in[wid];
    if (D == 128) {
        float2 bb = *(const float2*)(b + 2 * lane);
        float v0 = acc0 * ii + bb.x;
        float v1 = acc1 * ii + bb.y;
        if (RELU) {
            float io = inv_out[wid];
            v0 = fmaxf(v0, 0.0f) * io;
            v1 = fmaxf(v1, 0.0f) * io;
        }
        *(float2*)(out + (long long)wid * D + 2 * lane) = make_float2(v0, v1);
    } else {
        float v0 = acc0 * ii + b[lane];
        if (RELU) v0 = fmaxf(v0, 0.0f) * inv_out[wid];
        out[(long long)wid * D + lane] = v0;
    }
}

// ---------------------------------------------------------------- launch
extern "C" void kernel_launch(void* const* d_in, const int* in_sizes, int n_in,
                              void* d_out, int out_size, void* d_ws, size_t ws_size,
                              hipStream_t stream) {
    const int*   src = (const int*)d_in[0];
    const int*   dst = (const int*)d_in[1];
    const float* x   = (const float*)d_in[2];
    const float* W1  = (const float*)d_in[3];
    const float* b1  = (const float*)d_in[4];
    const float* W2  = (const float*)d_in[5];
    const float* b2  = (const float*)d_in[6];
    float* out = (float*)d_out;

    const int E = in_sizes[0];
    const int N = in_sizes[2] / D_IN;

    char* ws = (char*)d_ws;
    size_t off = 0;
    auto alloc = [&](size_t bytes) -> void* {
        void* p = ws + off;
        off += (bytes + 255) & ~(size_t)255;
        return p;
    };
    int*   hist_out = (int*)alloc((size_t)N * 4);
    int*   hist_in  = (int*)alloc((size_t)N * 4);
    float* inv_out  = (float*)alloc((size_t)N * 4);
    float* inv_in   = (float*)alloc((size_t)N * 4);
    int*   rowptr   = (int*)alloc((size_t)(N + 1) * 4);
    int*   cursor   = (int*)alloc((size_t)N * 4);
    int*   csr_src  = (int*)alloc((size_t)E * 4);
    float* Y1       = (float*)alloc((size_t)N * D_HID * 4);
    float* H        = (float*)alloc((size_t)N * D_HID * 4);
    float* Y2       = (float*)alloc((size_t)N * D_OUT * 4);
    (void)ws_size; (void)n_in; (void)out_size;

    hipMemsetAsync(hist_out, 0, (size_t)N * 4, stream);
    hipMemsetAsync(hist_in,  0, (size_t)N * 4, stream);

    // CSR build + degree norms
    k_hist<<<1024, 256, 0, stream>>>(src, dst, hist_out, hist_in, E);
    k_invsqrt<<<(N + 255) / 256, 256, 0, stream>>>(hist_out, hist_in, inv_out, inv_in, N);
    k_scan<<<1, SCAN_T, 0, stream>>>(hist_in, rowptr, cursor, N);
    k_fill<<<1024, 256, 0, stream>>>(src, dst, cursor, csr_src, E);

    // layer 1: Y1 = (x*inv_out)@W1 ; H = relu(gather(Y1)*inv_in + b1) * inv_out
    k_gemm<D_HID, 8><<<(N + 7) / 8, 256, 0, stream>>>(x, W1, inv_out, Y1, N);
    k_gather<D_HID, true><<<(N + 3) / 4, 256, 0, stream>>>(rowptr, csr_src, Y1, inv_in, inv_out, b1, H, N);

    // layer 2: Y2 = H@W2 ; out = gather(Y2)*inv_in + b2
    k_gemm<D_OUT, 8><<<(N + 7) / 8, 256, 0, stream>>>(H, W2, nullptr, Y2, N);
    k_gather<D_OUT, false><<<(N + 3) / 4, 256, 0, stream>>>(rowptr, csr_src, Y2, inv_in, nullptr, b2, out, N);
}

// Round 3
// 354.923 us; speedup vs baseline: 2.0851x; 1.3030x over previous
//
#include <hip/hip_runtime.h>

#define D_IN  128
#define D_HID 128
#define D_OUT 64
#define SC 1024   // scan: elements per block
#define SB 256    // scan: threads per block

// ---------------------------------------------------------------- histograms (int)
__global__ void k_hist(const int* __restrict__ src, const int* __restrict__ dst,
                       int* __restrict__ hist_out, int* __restrict__ hist_in, int E) {
    int i = blockIdx.x * blockDim.x + threadIdx.x;
    int stride = gridDim.x * blockDim.x;
    for (; i < E; i += stride) {
        atomicAdd(&hist_out[src[i]], 1);
        atomicAdd(&hist_in[dst[i]], 1);
    }
}

__global__ void k_invsqrt(const int* __restrict__ hist_out, const int* __restrict__ hist_in,
                          float* __restrict__ inv_out, float* __restrict__ inv_in, int N) {
    int i = blockIdx.x * blockDim.x + threadIdx.x;
    if (i < N) {
        inv_out[i] = rsqrtf((float)max(hist_out[i], 1));
        inv_in[i]  = rsqrtf((float)max(hist_in[i],  1));
    }
}

// ---------------------------------------------------------------- hierarchical scan
// (a) per-block (1024-elem chunk) sums
__launch_bounds__(SB)
__global__ void k_scan_sums(const int* __restrict__ hist, int* __restrict__ bsum, int N) {
    __shared__ int s[SB];
    const int t = threadIdx.x;
    const int base = blockIdx.x * SC + t * 4;
    int v = 0;
#pragma unroll
    for (int u = 0; u < 4; ++u) { int i = base + u; if (i < N) v += hist[i]; }
    s[t] = v; __syncthreads();
    for (int off = SB / 2; off > 0; off >>= 1) {
        if (t < off) s[t] += s[t + off];
        __syncthreads();
    }
    if (t == 0) bsum[blockIdx.x] = s[0];
}

// (b) one wave scans the <=64 block sums (exclusive), writes rowptr[N]=E
__launch_bounds__(64)
__global__ void k_scan_boff(const int* __restrict__ bsum, int* __restrict__ boff,
                            int B, int* __restrict__ rowptr_last, int E) {
    const int lane = threadIdx.x;
    int v = (lane < B) ? bsum[lane] : 0;
    int inc = v;
#pragma unroll
    for (int off = 1; off < 64; off <<= 1) {
        int o = __shfl_up(inc, off);
        if (lane >= off) inc += o;
    }
    if (lane < B) boff[lane] = inc - v;
    if (lane == 0) *rowptr_last = E;
}

// (c) per-block local exclusive scan + block offset -> rowptr, cursor
__launch_bounds__(SB)
__global__ void k_scan_apply(const int* __restrict__ hist, const int* __restrict__ boff,
                             int* __restrict__ rowptr, int* __restrict__ cursor, int N) {
    __shared__ int s[SB];
    const int t = threadIdx.x;
    const int base = blockIdx.x * SC + t * 4;
    int h[4]; int tsum = 0;
#pragma unroll
    for (int u = 0; u < 4; ++u) { int i = base + u; h[u] = (i < N) ? hist[i] : 0; tsum += h[u]; }
    s[t] = tsum; __syncthreads();
    int inc = tsum;
    for (int off = 1; off < SB; off <<= 1) {
        int o = (t >= off) ? s[t - off] : 0;
        __syncthreads();
        inc += o;
        s[t] = inc;
        __syncthreads();
    }
    int run = boff[blockIdx.x] + (inc - tsum);
#pragma unroll
    for (int u = 0; u < 4; ++u) {
        int i = base + u;
        if (i < N) { rowptr[i] = run; cursor[i] = run; run += h[u]; }
    }
}

// ---------------------------------------------------------------- CSR fill
__global__ void k_fill(const int* __restrict__ src, const int* __restrict__ dst,
                       int* __restrict__ cursor, int* __restrict__ csr_src, int E) {
    int i = blockIdx.x * blockDim.x + threadIdx.x;
    int stride = gridDim.x * blockDim.x;
    for (; i < E; i += stride) {
        int pos = atomicAdd(&cursor[dst[i]], 1);
        csr_src[pos] = src[i];
    }
}

// ---------------------------------------------------------------- GEMM
// Y[i][j] = sum_k X[i][k] * scale_i * W[k][j]      (scale optional)
template<int DOUT, int ROWS>
__launch_bounds__(256)
__global__ void k_gemm(const float* __restrict__ X, const float* __restrict__ W,
                       const float* __restrict__ scale, float* __restrict__ Y, int N) {
    __shared__ float Wl[64 * DOUT];       // half of W (k = 0..63 or 64..127)
    __shared__ float Xl[ROWS][D_IN];

    const int row0 = blockIdx.x * ROWS;

    for (int idx = threadIdx.x; idx < ROWS * D_IN; idx += 256) {
        int r = idx >> 7, c = idx & 127;
        int gr = row0 + r;
        float v = 0.0f;
        if (gr < N) {
            v = X[(long long)gr * D_IN + c];
            if (scale) v *= scale[gr];
        }
        Xl[r][c] = v;
    }

    const int j  = threadIdx.x % DOUT;
    const int rg = threadIdx.x / DOUT;
    constexpr int RG = 256 / DOUT;
    constexpr int M  = ROWS / RG;

    float acc[M];
#pragma unroll
    for (int m = 0; m < M; ++m) acc[m] = 0.0f;

#pragma unroll
    for (int half = 0; half < 2; ++half) {
        __syncthreads();
        for (int idx = threadIdx.x; idx < 64 * DOUT; idx += 256)
            Wl[idx] = W[half * 64 * DOUT + idx];
        __syncthreads();
#pragma unroll 4
        for (int k = 0; k < 64; ++k) {
            float w = Wl[k * DOUT + j];
#pragma unroll
            for (int m = 0; m < M; ++m)
                acc[m] += Xl[rg * M + m][half * 64 + k] * w;
        }
    }

#pragma unroll
    for (int m = 0; m < M; ++m) {
        int gr = row0 + rg * M + m;
        if (gr < N) Y[(long long)gr * DOUT + j] = acc[m];
    }
}

// ---------------------------------------------------------------- CSR gather
// out[i] = f( sum_{e in CSR(i)} Y[csr_src[e]] )
// One wave (64 lanes) per destination node. D=128: 2 floats/lane; D=64: 1.
template<int D, bool RELU>
__launch_bounds__(256)
__global__ void k_gather(const int* __restrict__ rowptr, const int* __restrict__ csr_src,
                         const float* __restrict__ Y, const float* __restrict__ inv_in,
                         const float* __restrict__ inv_out, const float* __restrict__ b,
                         float* __restrict__ out, int N) {
    const int wid  = (int)((blockIdx.x * 256u + threadIdx.x) >> 6);
    const int lane = threadIdx.x & 63;
    if (wid >= N) return;

    const int start = rowptr[wid];
    const int end   = rowptr[wid + 1];

    float acc0 = 0.0f, acc1 = 0.0f;
    for (int k = start; k < end; k += 64) {
        const int idx = k + lane;
        const int sv  = (idx < end) ? csr_src[idx] : 0;
        const int cnt = min(64, end - k);
        for (int j = 0; j < cnt; ++j) {
            const int s = __shfl(sv, j);
            if (D == 128) {
                float2 v = *(const float2*)(Y + (long long)s * D + 2 * lane);
                acc0 += v.x; acc1 += v.y;
            } else {
                acc0 += Y[(long long)s * D + lane];
            }
        }
    }

    const float ii = inv_in[wid];
    if (D == 128) {
        float2 bb = *(const float2*)(b + 2 * lane);
        float v0 = acc0 * ii + bb.x;
        float v1 = acc1 * ii + bb.y;
        if (RELU) {
            float io = inv_out[wid];
            v0 = fmaxf(v0, 0.0f) * io;
            v1 = fmaxf(v1, 0.0f) * io;
        }
        *(float2*)(out + (long long)wid * D + 2 * lane) = make_float2(v0, v1);
    } else {
        float v0 = acc0 * ii + b[lane];
        if (RELU) v0 = fmaxf(v0, 0.0f) * inv_out[wid];
        out[(long long)wid * D + lane] = v0;
    }
}

// ---------------------------------------------------------------- launch
extern "C" void kernel_launch(void* const* d_in, const int* in_sizes, int n_in,
                              void* d_out, int out_size, void* d_ws, size_t ws_size,
                              hipStream_t stream) {
    const int*   src = (const int*)d_in[0];
    const int*   dst = (const int*)d_in[1];
    const float* x   = (const float*)d_in[2];
    const float* W1  = (const float*)d_in[3];
    const float* b1  = (const float*)d_in[4];
    const float* W2  = (const float*)d_in[5];
    const float* b2  = (const float*)d_in[6];
    float* out = (float*)d_out;

    const int E = in_sizes[0];
    const int N = in_sizes[2] / D_IN;
    const int B = (N + SC - 1) / SC;   // <= 64 for N <= 65536

    char* ws = (char*)d_ws;
    size_t off = 0;
    auto alloc = [&](size_t bytes) -> void* {
        void* p = ws + off;
        off += (bytes + 255) & ~(size_t)255;
        return p;
    };
    int*   hist_out = (int*)alloc((size_t)N * 4);
    int*   hist_in  = (int*)alloc((size_t)N * 4);
    float* inv_out  = (float*)alloc((size_t)N * 4);
    float* inv_in   = (float*)alloc((size_t)N * 4);
    int*   rowptr   = (int*)alloc((size_t)(N + 1) * 4);
    int*   cursor   = (int*)alloc((size_t)N * 4);
    int*   bsum     = (int*)alloc(64 * 4);
    int*   boff     = (int*)alloc(64 * 4);
    int*   csr_src  = (int*)alloc((size_t)E * 4);
    float* Y1       = (float*)alloc((size_t)N * D_HID * 4);
    float* H        = (float*)alloc((size_t)N * D_HID * 4);
    float* Y2       = (float*)alloc((size_t)N * D_OUT * 4);
    (void)ws_size; (void)n_in; (void)out_size;

    hipMemsetAsync(hist_out, 0, (size_t)N * 4, stream);
    hipMemsetAsync(hist_in,  0, (size_t)N * 4, stream);

    // CSR build + degree norms
    k_hist<<<1024, 256, 0, stream>>>(src, dst, hist_out, hist_in, E);
    k_invsqrt<<<(N + 255) / 256, 256, 0, stream>>>(hist_out, hist_in, inv_out, inv_in, N);
    k_scan_sums<<<B, SB, 0, stream>>>(hist_in, bsum, N);
    k_scan_boff<<<1, 64, 0, stream>>>(bsum, boff, B, rowptr + N, E);
    k_scan_apply<<<B, SB, 0, stream>>>(hist_in, boff, rowptr, cursor, N);
    k_fill<<<1024, 256, 0, stream>>>(src, dst, cursor, csr_src, E);

    // layer 1: Y1 = (x*inv_out)@W1 ; H = relu(gather(Y1)*inv_in + b1) * inv_out
    k_gemm<D_HID, 16><<<(N + 15) / 16, 256, 0, stream>>>(x, W1, inv_out, Y1, N);
    k_gather<D_HID, true><<<(N + 3) / 4, 256, 0, stream>>>(rowptr, csr_src, Y1, inv_in, inv_out, b1, H, N);

    // layer 2: Y2 = H@W2 ; out = gather(Y2)*inv_in + b2
    k_gemm<D_OUT, 16><<<(N + 15) / 16, 256, 0, stream>>>(H, W2, nullptr, Y2, N);
    k_gather<D_OUT, false><<<(N + 3) / 4, 256, 0, stream>>>(rowptr, csr_src, Y2, inv_in, nullptr, b2, out, N);
}

// Round 4
// 252.296 us; speedup vs baseline: 2.9333x; 1.4068x over previous
//
#include <hip/hip_runtime.h>

#define D_IN  128
#define D_HID 128
#define D_OUT 64
#define NBMAX 512      // max buckets (N <= 65536)
#define CHUNK 4096     // edges per k_bucket block

// ---------------------------------------------------------------- bucket scatter
// Counting-sort pass 1: scatter edges into 128-node dst-buckets (int2 src,dst)
// and src values into 128-node src-buckets. LDS-aggregated reservations.
__launch_bounds__(256)
__global__ void k_bucket(const int* __restrict__ src, const int* __restrict__ dst,
                         int E, int NB, int cap,
                         int* __restrict__ cntD, int* __restrict__ cntS,
                         int2* __restrict__ storeD, int* __restrict__ storeS) {
    __shared__ int lcD[NBMAX], lcS[NBMAX];
    __shared__ int lbD[NBMAX], lbS[NBMAX];
    const int t = threadIdx.x;
    const int e0 = blockIdx.x * CHUNK;
    const int e1 = min(e0 + CHUNK, E);

    for (int i = t; i < NB; i += 256) { lcD[i] = 0; lcS[i] = 0; }
    __syncthreads();
    for (int i = e0 + t; i < e1; i += 256) {
        atomicAdd(&lcD[dst[i] >> 7], 1);
        atomicAdd(&lcS[src[i] >> 7], 1);
    }
    __syncthreads();
    for (int i = t; i < NB; i += 256) {
        lbD[i] = lcD[i] ? atomicAdd(&cntD[i], lcD[i]) : 0;
        lbS[i] = lcS[i] ? atomicAdd(&cntS[i], lcS[i]) : 0;
        lcD[i] = 0; lcS[i] = 0;
    }
    __syncthreads();
    for (int i = e0 + t; i < e1; i += 256) {
        const int s = src[i], d = dst[i];
        const int bd = d >> 7;
        const int pd = lbD[bd] + atomicAdd(&lcD[bd], 1);
        storeD[(long long)bd * cap + pd] = make_int2(s, d);
        const int bs = s >> 7;
        const int ps = lbS[bs] + atomicAdd(&lcS[bs], 1);
        storeS[(long long)bs * cap + ps] = s;
    }
}

// ---------------------------------------------------------------- bucket scan
__launch_bounds__(512)
__global__ void k_scan512(const int* __restrict__ cntD, int* __restrict__ coarse_off,
                          int NB, int* __restrict__ rowptr_last, int E) {
    __shared__ int sh[512];
    const int t = threadIdx.x;
    const int v = (t < NB) ? cntD[t] : 0;
    sh[t] = v; __syncthreads();
    int inc = v;
    for (int off = 1; off < 512; off <<= 1) {
        int o = (t >= off) ? sh[t - off] : 0;
        __syncthreads();
        inc += o; sh[t] = inc;
        __syncthreads();
    }
    if (t < NB) coarse_off[t] = inc - v;
    if (t == 0) *rowptr_last = E;
}

// ---------------------------------------------------------------- finalize
// Per dst-bucket: 128-bin LDS histogram + scan -> rowptr, inv_in, csr_src.
// Then per src-bucket: histogram -> inv_out.
__launch_bounds__(256)
__global__ void k_fin(const int2* __restrict__ storeD, const int* __restrict__ storeS,
                      const int* __restrict__ cntD, const int* __restrict__ cntS,
                      const int* __restrict__ coarse_off, int cap, int N,
                      int* __restrict__ rowptr, float* __restrict__ inv_in,
                      float* __restrict__ inv_out, int* __restrict__ csr_src) {
    __shared__ int fh[128];
    __shared__ int sc[128];
    __shared__ int cur[128];
    const int b = blockIdx.x, t = threadIdx.x;
    const long long sb = (long long)b * cap;

    // ---- dst side: rowptr / inv_in / csr_src
    const int cnt  = cntD[b];
    const int base = coarse_off[b];
    if (t < 128) fh[t] = 0;
    __syncthreads();
    for (int i = t; i < cnt; i += 256) atomicAdd(&fh[storeD[sb + i].y & 127], 1);
    __syncthreads();
    if (t < 128) sc[t] = fh[t];
    __syncthreads();
    int inc = (t < 128) ? sc[t] : 0;
    for (int off = 1; off < 128; off <<= 1) {
        int o = (t >= off && t < 128) ? sc[t - off] : 0;
        __syncthreads();
        if (t < 128) { inc += o; sc[t] = inc; }
        __syncthreads();
    }
    if (t < 128) {
        const int excl = inc - fh[t];
        cur[t] = excl;
        const int node = (b << 7) + t;
        if (node < N) {
            rowptr[node] = base + excl;
            inv_in[node] = rsqrtf((float)max(fh[t], 1));
        }
    }
    __syncthreads();
    for (int i = t; i < cnt; i += 256) {
        const int2 e = storeD[sb + i];
        const int pos = atomicAdd(&cur[e.y & 127], 1);
        csr_src[base + pos] = e.x;
    }

    // ---- src side: inv_out
    __syncthreads();
    if (t < 128) fh[t] = 0;
    __syncthreads();
    const int cnts = cntS[b];
    for (int i = t; i < cnts; i += 256) atomicAdd(&fh[storeS[sb + i] & 127], 1);
    __syncthreads();
    if (t < 128) {
        const int node = (b << 7) + t;
        if (node < N) inv_out[node] = rsqrtf((float)max(fh[t], 1));
    }
}

// ---------------------------------------------------------------- GEMM
// Y[i][j] = sum_k X[i][k] * scale_i * W[k][j]      (scale optional)
template<int DOUT, int ROWS>
__launch_bounds__(256)
__global__ void k_gemm(const float* __restrict__ X, const float* __restrict__ W,
                       const float* __restrict__ scale, float* __restrict__ Y, int N) {
    __shared__ float Wl[64 * DOUT];       // half of W (k = 0..63 or 64..127)
    __shared__ float Xl[ROWS][D_IN];

    const int row0 = blockIdx.x * ROWS;

    for (int idx = threadIdx.x; idx < ROWS * D_IN; idx += 256) {
        int r = idx >> 7, c = idx & 127;
        int gr = row0 + r;
        float v = 0.0f;
        if (gr < N) {
            v = X[(long long)gr * D_IN + c];
            if (scale) v *= scale[gr];
        }
        Xl[r][c] = v;
    }

    const int j  = threadIdx.x % DOUT;
    const int rg = threadIdx.x / DOUT;
    constexpr int RG = 256 / DOUT;
    constexpr int M  = ROWS / RG;

    float acc[M];
#pragma unroll
    for (int m = 0; m < M; ++m) acc[m] = 0.0f;

#pragma unroll
    for (int half = 0; half < 2; ++half) {
        __syncthreads();
        for (int idx = threadIdx.x; idx < 64 * DOUT; idx += 256)
            Wl[idx] = W[half * 64 * DOUT + idx];
        __syncthreads();
#pragma unroll 4
        for (int k = 0; k < 64; ++k) {
            float w = Wl[k * DOUT + j];
#pragma unroll
            for (int m = 0; m < M; ++m)
                acc[m] += Xl[rg * M + m][half * 64 + k] * w;
        }
    }

#pragma unroll
    for (int m = 0; m < M; ++m) {
        int gr = row0 + rg * M + m;
        if (gr < N) Y[(long long)gr * DOUT + j] = acc[m];
    }
}

// ---------------------------------------------------------------- CSR gather
template<int D, bool RELU>
__launch_bounds__(256)
__global__ void k_gather(const int* __restrict__ rowptr, const int* __restrict__ csr_src,
                         const float* __restrict__ Y, const float* __restrict__ inv_in,
                         const float* __restrict__ inv_out, const float* __restrict__ b,
                         float* __restrict__ out, int N) {
    const int wid  = (int)((blockIdx.x * 256u + threadIdx.x) >> 6);
    const int lane = threadIdx.x & 63;
    if (wid >= N) return;

    const int start = rowptr[wid];
    const int end   = rowptr[wid + 1];

    float acc0 = 0.0f, acc1 = 0.0f;
    for (int k = start; k < end; k += 64) {
        const int idx = k + lane;
        const int sv  = (idx < end) ? csr_src[idx] : 0;
        const int cnt = min(64, end - k);
        for (int j = 0; j < cnt; ++j) {
            const int s = __shfl(sv, j);
            if (D == 128) {
                float2 v = *(const float2*)(Y + (long long)s * D + 2 * lane);
                acc0 += v.x; acc1 += v.y;
            } else {
                acc0 += Y[(long long)s * D + lane];
            }
        }
    }

    const float ii = inv_in[wid];
    if (D == 128) {
        float2 bb = *(const float2*)(b + 2 * lane);
        float v0 = acc0 * ii + bb.x;
        float v1 = acc1 * ii + bb.y;
        if (RELU) {
            float io = inv_out[wid];
            v0 = fmaxf(v0, 0.0f) * io;
            v1 = fmaxf(v1, 0.0f) * io;
        }
        *(float2*)(out + (long long)wid * D + 2 * lane) = make_float2(v0, v1);
    } else {
        float v0 = acc0 * ii + b[lane];
        if (RELU) v0 = fmaxf(v0, 0.0f) * inv_out[wid];
        out[(long long)wid * D + lane] = v0;
    }
}

// ---------------------------------------------------------------- launch
extern "C" void kernel_launch(void* const* d_in, const int* in_sizes, int n_in,
                              void* d_out, int out_size, void* d_ws, size_t ws_size,
                              hipStream_t stream) {
    const int*   src = (const int*)d_in[0];
    const int*   dst = (const int*)d_in[1];
    const float* x   = (const float*)d_in[2];
    const float* W1  = (const float*)d_in[3];
    const float* b1  = (const float*)d_in[4];
    const float* W2  = (const float*)d_in[5];
    const float* b2  = (const float*)d_in[6];
    float* out = (float*)d_out;

    const int E  = in_sizes[0];
    const int N  = in_sizes[2] / D_IN;
    const int NB = (N + 127) >> 7;                 // 128-node buckets (<= NBMAX)
    const int mean = E / NB;
    const int cap  = mean + mean / 4 + 128;        // generous multinomial margin

    char* ws = (char*)d_ws;
    size_t off = 0;
    auto alloc = [&](size_t bytes) -> void* {
        void* p = ws + off;
        off += (bytes + 255) & ~(size_t)255;
        return p;
    };
    float* inv_out  = (float*)alloc((size_t)N * 4);
    float* inv_in   = (float*)alloc((size_t)N * 4);
    int*   rowptr   = (int*)alloc((size_t)(N + 1) * 4);
    int*   cntD     = (int*)alloc((size_t)NB * 4);
    int*   cntS     = (int*)alloc((size_t)NB * 4);
    int*   coarse   = (int*)alloc((size_t)NB * 4);
    int2*  storeD   = (int2*)alloc((size_t)NB * cap * 8);
    int*   storeS   = (int*)alloc((size_t)NB * cap * 4);
    int*   csr_src  = (int*)alloc((size_t)E * 4);
    float* Y1       = (float*)alloc((size_t)N * D_HID * 4);
    float* H        = (float*)alloc((size_t)N * D_HID * 4);
    float* Y2       = (float*)alloc((size_t)N * D_OUT * 4);
    (void)ws_size; (void)n_in; (void)out_size;

    hipMemsetAsync(cntD, 0, (size_t)NB * 4, stream);
    hipMemsetAsync(cntS, 0, (size_t)NB * 4, stream);

    // CSR build + degree norms (counting sort, LDS-aggregated)
    k_bucket<<<(E + CHUNK - 1) / CHUNK, 256, 0, stream>>>(src, dst, E, NB, cap, cntD, cntS, storeD, storeS);
    k_scan512<<<1, 512, 0, stream>>>(cntD, coarse, NB, rowptr + N, E);
    k_fin<<<NB, 256, 0, stream>>>(storeD, storeS, cntD, cntS, coarse, cap, N,
                                  rowptr, inv_in, inv_out, csr_src);

    // layer 1: Y1 = (x*inv_out)@W1 ; H = relu(gather(Y1)*inv_in + b1) * inv_out
    k_gemm<D_HID, 16><<<(N + 15) / 16, 256, 0, stream>>>(x, W1, inv_out, Y1, N);
    k_gather<D_HID, true><<<(N + 3) / 4, 256, 0, stream>>>(rowptr, csr_src, Y1, inv_in, inv_out, b1, H, N);

    // layer 2: Y2 = H@W2 ; out = gather(Y2)*inv_in + b2
    k_gemm<D_OUT, 16><<<(N + 15) / 16, 256, 0, stream>>>(H, W2, nullptr, Y2, N);
    k_gather<D_OUT, false><<<(N + 3) / 4, 256, 0, stream>>>(rowptr, csr_src, Y2, inv_in, nullptr, b2, out, N);
}

// Round 5
// 226.472 us; speedup vs baseline: 3.2677x; 1.1140x over previous
//
#include <hip/hip_runtime.h>

#define D_IN  128
#define D_HID 128
#define D_OUT 64
#define NBMAX 512      // max buckets (N <= 65536)
#define CHUNK 4096     // edges per k_bucket block

// ---------------------------------------------------------------- bucket scatter
// Counting-sort pass 1: scatter edges into 128-node dst-buckets (int2 src,dst)
// and src values into 128-node src-buckets. LDS-aggregated reservations.
__launch_bounds__(256)
__global__ void k_bucket(const int* __restrict__ src, const int* __restrict__ dst,
                         int E, int NB, int cap,
                         int* __restrict__ cntD, int* __restrict__ cntS,
                         int2* __restrict__ storeD, int* __restrict__ storeS) {
    __shared__ int lcD[NBMAX], lcS[NBMAX];
    __shared__ int lbD[NBMAX], lbS[NBMAX];
    const int t = threadIdx.x;
    const int e0 = blockIdx.x * CHUNK;
    const int e1 = min(e0 + CHUNK, E);

    for (int i = t; i < NB; i += 256) { lcD[i] = 0; lcS[i] = 0; }
    __syncthreads();
    for (int i = e0 + t; i < e1; i += 256) {
        atomicAdd(&lcD[dst[i] >> 7], 1);
        atomicAdd(&lcS[src[i] >> 7], 1);
    }
    __syncthreads();
    for (int i = t; i < NB; i += 256) {
        lbD[i] = lcD[i] ? atomicAdd(&cntD[i], lcD[i]) : 0;
        lbS[i] = lcS[i] ? atomicAdd(&cntS[i], lcS[i]) : 0;
        lcD[i] = 0; lcS[i] = 0;
    }
    __syncthreads();
    for (int i = e0 + t; i < e1; i += 256) {
        const int s = src[i], d = dst[i];
        const int bd = d >> 7;
        const int pd = lbD[bd] + atomicAdd(&lcD[bd], 1);
        storeD[(long long)bd * cap + pd] = make_int2(s, d);
        const int bs = s >> 7;
        const int ps = lbS[bs] + atomicAdd(&lcS[bs], 1);
        storeS[(long long)bs * cap + ps] = s;
    }
}

// ---------------------------------------------------------------- bucket scan
__launch_bounds__(512)
__global__ void k_scan512(const int* __restrict__ cntD, int* __restrict__ coarse_off,
                          int NB, int* __restrict__ rowptr_last, int E) {
    __shared__ int sh[512];
    const int t = threadIdx.x;
    const int v = (t < NB) ? cntD[t] : 0;
    sh[t] = v; __syncthreads();
    int inc = v;
    for (int off = 1; off < 512; off <<= 1) {
        int o = (t >= off) ? sh[t - off] : 0;
        __syncthreads();
        inc += o; sh[t] = inc;
        __syncthreads();
    }
    if (t < NB) coarse_off[t] = inc - v;
    if (t == 0) *rowptr_last = E;
}

// ---------------------------------------------------------------- finalize
// Per dst-bucket: 128-bin LDS histogram + scan -> rowptr, inv_in, csr_src.
// Then per src-bucket: histogram -> inv_out.
__launch_bounds__(256)
__global__ void k_fin(const int2* __restrict__ storeD, const int* __restrict__ storeS,
                      const int* __restrict__ cntD, const int* __restrict__ cntS,
                      const int* __restrict__ coarse_off, int cap, int N,
                      int* __restrict__ rowptr, float* __restrict__ inv_in,
                      float* __restrict__ inv_out, int* __restrict__ csr_src) {
    __shared__ int fh[128];
    __shared__ int sc[128];
    __shared__ int cur[128];
    const int b = blockIdx.x, t = threadIdx.x;
    const long long sb = (long long)b * cap;

    // ---- dst side: rowptr / inv_in / csr_src
    const int cnt  = cntD[b];
    const int base = coarse_off[b];
    if (t < 128) fh[t] = 0;
    __syncthreads();
    for (int i = t; i < cnt; i += 256) atomicAdd(&fh[storeD[sb + i].y & 127], 1);
    __syncthreads();
    if (t < 128) sc[t] = fh[t];
    __syncthreads();
    int inc = (t < 128) ? sc[t] : 0;
    for (int off = 1; off < 128; off <<= 1) {
        int o = (t >= off && t < 128) ? sc[t - off] : 0;
        __syncthreads();
        if (t < 128) { inc += o; sc[t] = inc; }
        __syncthreads();
    }
    if (t < 128) {
        const int excl = inc - fh[t];
        cur[t] = excl;
        const int node = (b << 7) + t;
        if (node < N) {
            rowptr[node] = base + excl;
            inv_in[node] = rsqrtf((float)max(fh[t], 1));
        }
    }
    __syncthreads();
    for (int i = t; i < cnt; i += 256) {
        const int2 e = storeD[sb + i];
        const int pos = atomicAdd(&cur[e.y & 127], 1);
        csr_src[base + pos] = e.x;
    }

    // ---- src side: inv_out
    __syncthreads();
    if (t < 128) fh[t] = 0;
    __syncthreads();
    const int cnts = cntS[b];
    for (int i = t; i < cnts; i += 256) atomicAdd(&fh[storeS[sb + i] & 127], 1);
    __syncthreads();
    if (t < 128) {
        const int node = (b << 7) + t;
        if (node < N) inv_out[node] = rsqrtf((float)max(fh[t], 1));
    }
}

// ---------------------------------------------------------------- GEMM
// Y[i][j] = sum_k X[i][k] * scale_i * W[k][j]      (scale optional)
template<int DOUT, int ROWS>
__launch_bounds__(256)
__global__ void k_gemm(const float* __restrict__ X, const float* __restrict__ W,
                       const float* __restrict__ scale, float* __restrict__ Y, int N) {
    __shared__ float Wl[64 * DOUT];       // half of W (k = 0..63 or 64..127)
    __shared__ float Xl[ROWS][D_IN];

    const int row0 = blockIdx.x * ROWS;

    for (int idx = threadIdx.x; idx < ROWS * D_IN; idx += 256) {
        int r = idx >> 7, c = idx & 127;
        int gr = row0 + r;
        float v = 0.0f;
        if (gr < N) {
            v = X[(long long)gr * D_IN + c];
            if (scale) v *= scale[gr];
        }
        Xl[r][c] = v;
    }

    const int j  = threadIdx.x % DOUT;
    const int rg = threadIdx.x / DOUT;
    constexpr int RG = 256 / DOUT;
    constexpr int M  = ROWS / RG;

    float acc[M];
#pragma unroll
    for (int m = 0; m < M; ++m) acc[m] = 0.0f;

#pragma unroll
    for (int half = 0; half < 2; ++half) {
        __syncthreads();
        for (int idx = threadIdx.x; idx < 64 * DOUT; idx += 256)
            Wl[idx] = W[half * 64 * DOUT + idx];
        __syncthreads();
#pragma unroll 4
        for (int k = 0; k < 64; ++k) {
            float w = Wl[k * DOUT + j];
#pragma unroll
            for (int m = 0; m < M; ++m)
                acc[m] += Xl[rg * M + m][half * 64 + k] * w;
        }
    }

#pragma unroll
    for (int m = 0; m < M; ++m) {
        int gr = row0 + rg * M + m;
        if (gr < N) Y[(long long)gr * DOUT + j] = acc[m];
    }
}

// ---------------------------------------------------------------- CSR gather
// One wave per destination node; EPW edges in flight (float4 per lane):
//   D=128: 2 edges x 32 lanes;  D=64: 4 edges x 16 lanes.
template<int D, bool RELU>
__launch_bounds__(256)
__global__ void k_gather(const int* __restrict__ rowptr, const int* __restrict__ csr_src,
                         const float* __restrict__ Y, const float* __restrict__ inv_in,
                         const float* __restrict__ inv_out, const float* __restrict__ b,
                         float* __restrict__ out, int N) {
    const int wid  = (int)((blockIdx.x * 256u + threadIdx.x) >> 6);
    const int lane = threadIdx.x & 63;
    if (wid >= N) return;

    const int start = rowptr[wid];
    const int end   = rowptr[wid + 1];

    constexpr int LPE = D / 4;            // lanes per edge (32 or 16)
    constexpr int EPW = 64 / LPE;         // edges in flight  (2 or 4)
    const int grp  = lane / LPE;          // 0..EPW-1
    const int col4 = (lane % LPE) * 4;

    float4 acc = make_float4(0.f, 0.f, 0.f, 0.f);
    for (int k = start; k < end; k += 64) {
        const int idx = k + lane;
        const int sv  = (idx < end) ? csr_src[idx] : 0;
        const int cnt = min(64, end - k);
        for (int j = 0; j < cnt; j += EPW) {
            const int jj = j + grp;
            const int s  = __shfl(sv, jj);
            if (jj < cnt) {
                float4 v = *(const float4*)(Y + (long long)s * D + col4);
                acc.x += v.x; acc.y += v.y; acc.z += v.z; acc.w += v.w;
            }
        }
    }

    // combine the EPW edge groups (they hold the same columns)
    acc.x += __shfl_down(acc.x, 32); acc.y += __shfl_down(acc.y, 32);
    acc.z += __shfl_down(acc.z, 32); acc.w += __shfl_down(acc.w, 32);
    if (EPW == 4) {
        acc.x += __shfl_down(acc.x, 16); acc.y += __shfl_down(acc.y, 16);
        acc.z += __shfl_down(acc.z, 16); acc.w += __shfl_down(acc.w, 16);
    }

    if (lane < LPE) {
        const float ii = inv_in[wid];
        const float4 bb = *(const float4*)(b + col4);
        float4 r;
        r.x = acc.x * ii + bb.x;
        r.y = acc.y * ii + bb.y;
        r.z = acc.z * ii + bb.z;
        r.w = acc.w * ii + bb.w;
        if (RELU) {
            const float io = inv_out[wid];
            r.x = fmaxf(r.x, 0.0f) * io;
            r.y = fmaxf(r.y, 0.0f) * io;
            r.z = fmaxf(r.z, 0.0f) * io;
            r.w = fmaxf(r.w, 0.0f) * io;
        }
        *(float4*)(out + (long long)wid * D + col4) = r;
    }
}

// ---------------------------------------------------------------- launch
extern "C" void kernel_launch(void* const* d_in, const int* in_sizes, int n_in,
                              void* d_out, int out_size, void* d_ws, size_t ws_size,
                              hipStream_t stream) {
    const int*   src = (const int*)d_in[0];
    const int*   dst = (const int*)d_in[1];
    const float* x   = (const float*)d_in[2];
    const float* W1  = (const float*)d_in[3];
    const float* b1  = (const float*)d_in[4];
    const float* W2  = (const float*)d_in[5];
    const float* b2  = (const float*)d_in[6];
    float* out = (float*)d_out;

    const int E  = in_sizes[0];
    const int N  = in_sizes[2] / D_IN;
    const int NB = (N + 127) >> 7;                 // 128-node buckets (<= NBMAX)
    const int mean = E / NB;
    const int cap  = mean + mean / 4 + 128;        // generous multinomial margin

    char* ws = (char*)d_ws;
    size_t off = 0;
    auto alloc = [&](size_t bytes) -> void* {
        void* p = ws + off;
        off += (bytes + 255) & ~(size_t)255;
        return p;
    };
    float* inv_out  = (float*)alloc((size_t)N * 4);
    float* inv_in   = (float*)alloc((size_t)N * 4);
    int*   rowptr   = (int*)alloc((size_t)(N + 1) * 4);
    int*   cntD     = (int*)alloc((size_t)NB * 4);
    int*   cntS     = (int*)alloc((size_t)NB * 4);
    int*   coarse   = (int*)alloc((size_t)NB * 4);
    int2*  storeD   = (int2*)alloc((size_t)NB * cap * 8);
    int*   storeS   = (int*)alloc((size_t)NB * cap * 4);
    int*   csr_src  = (int*)alloc((size_t)E * 4);
    float* Y1       = (float*)alloc((size_t)N * D_HID * 4);
    float* H        = (float*)alloc((size_t)N * D_HID * 4);
    float* Y2       = (float*)alloc((size_t)N * D_OUT * 4);
    (void)ws_size; (void)n_in; (void)out_size;

    hipMemsetAsync(cntD, 0, (size_t)NB * 4, stream);
    hipMemsetAsync(cntS, 0, (size_t)NB * 4, stream);

    // CSR build + degree norms (counting sort, LDS-aggregated)
    k_bucket<<<(E + CHUNK - 1) / CHUNK, 256, 0, stream>>>(src, dst, E, NB, cap, cntD, cntS, storeD, storeS);
    k_scan512<<<1, 512, 0, stream>>>(cntD, coarse, NB, rowptr + N, E);
    k_fin<<<NB, 256, 0, stream>>>(storeD, storeS, cntD, cntS, coarse, cap, N,
                                  rowptr, inv_in, inv_out, csr_src);

    // layer 1: Y1 = (x*inv_out)@W1 ; H = relu(gather(Y1)*inv_in + b1) * inv_out
    k_gemm<D_HID, 32><<<(N + 31) / 32, 256, 0, stream>>>(x, W1, inv_out, Y1, N);
    k_gather<D_HID, true><<<(N + 3) / 4, 256, 0, stream>>>(rowptr, csr_src, Y1, inv_in, inv_out, b1, H, N);

    // layer 2: Y2 = H@W2 ; out = gather(Y2)*inv_in + b2
    k_gemm<D_OUT, 32><<<(N + 31) / 32, 256, 0, stream>>>(H, W2, nullptr, Y2, N);
    k_gather<D_OUT, false><<<(N + 3) / 4, 256, 0, stream>>>(rowptr, csr_src, Y2, inv_in, nullptr, b2, out, N);
}